// Round 5
// baseline (251.087 us; speedup 1.0000x reference)
//
#include <hip/hip_runtime.h>
#include <hip/hip_fp16.h>
#include <hip/hip_bf16.h>

typedef __bf16 bf16x8 __attribute__((ext_vector_type(8)));
typedef float f32x4 __attribute__((ext_vector_type(4)));
typedef unsigned short ushort8 __attribute__((ext_vector_type(8)));

#define TM 128
#define TN 128
#define TK 64
#define FP8MAX 448.0f

// ---------------- amax stage 1: per-block max |x| over f32 input ----------------
__global__ __launch_bounds__(256)
void amax_stage1(const float* __restrict__ in, unsigned n4,
                 float* __restrict__ blockmax) {
    __shared__ float wmax[4];
    unsigned tid = blockIdx.x * 256 + threadIdx.x;
    unsigned stride = gridDim.x * 256;
    float m = 0.f;
    for (unsigned i = tid; i < n4; i += stride) {
        float4 v = *(const float4*)(in + (size_t)i * 4);
        m = fmaxf(m, fmaxf(fmaxf(fabsf(v.x), fabsf(v.y)), fmaxf(fabsf(v.z), fabsf(v.w))));
    }
#pragma unroll
    for (int off = 32; off > 0; off >>= 1)
        m = fmaxf(m, __shfl_down(m, off));
    if ((threadIdx.x & 63) == 0) wmax[threadIdx.x >> 6] = m;
    __syncthreads();
    if (threadIdx.x == 0)
        blockmax[blockIdx.x] = fmaxf(fmaxf(wmax[0], wmax[1]), fmaxf(wmax[2], wmax[3]));
}

// ---------------- amax stage 2: block b reduces bm[b*n .. b*n+n) -> outv[b] ----------------
__global__ __launch_bounds__(256)
void amax_stage2(const float* __restrict__ bm, int n, float* __restrict__ outv) {
    __shared__ float wmax[4];
    const float* p = bm + (size_t)blockIdx.x * n;
    float m = 0.f;
    for (int i = threadIdx.x; i < n; i += 256) m = fmaxf(m, p[i]);
#pragma unroll
    for (int off = 32; off > 0; off >>= 1)
        m = fmaxf(m, __shfl_down(m, off));
    if ((threadIdx.x & 63) == 0) wmax[threadIdx.x >> 6] = m;
    __syncthreads();
    if (threadIdx.x == 0)
        outv[blockIdx.x] = fmaxf(fmaxf(wmax[0], wmax[1]), fmaxf(wmax[2], wmax[3]));
}

// quantize 8 f32 -> e4m3 (HW RNE, OCP) -> exact bf16 bits
__device__ inline ushort8 quant8f(float4 lo, float4 hi, float scale) {
    float f[8] = {lo.x, lo.y, lo.z, lo.w, hi.x, hi.y, hi.z, hi.w};
    ushort8 r;
#pragma unroll
    for (int j = 0; j < 4; ++j) {
        float f0 = fminf(fmaxf(f[2 * j] * scale, -FP8MAX), FP8MAX);
        float f1 = fminf(fmaxf(f[2 * j + 1] * scale, -FP8MAX), FP8MAX);
        unsigned pk = __builtin_amdgcn_cvt_pk_fp8_f32(f0, f1, 0u, false);
        float d0 = __builtin_amdgcn_cvt_f32_fp8(pk, 0);
        float d1 = __builtin_amdgcn_cvt_f32_fp8(pk, 1);
        r[2 * j]     = (unsigned short)(__float_as_uint(d0) >> 16);  // e4m3 exact in bf16
        r[2 * j + 1] = (unsigned short)(__float_as_uint(d1) >> 16);
    }
    return r;
}

// ---------------- quantize kernel: f32 -> bf16(e4m3) into workspace ----------------
__global__ __launch_bounds__(256)
void quant_kernel(const float* __restrict__ in, ushort8* __restrict__ out,
                  const float* __restrict__ amax_p, unsigned n8) {
    float amax = fmaxf(*amax_p, 1e-12f);
    float scale = FP8MAX / amax;
    unsigned tid = blockIdx.x * 256 + threadIdx.x;
    unsigned stride = gridDim.x * 256;
    for (unsigned i = tid; i < n8; i += stride) {
        float4 lo = *(const float4*)(in + (size_t)i * 8);
        float4 hi = *(const float4*)(in + (size_t)i * 8 + 4);
        out[i] = quant8f(lo, hi, scale);
    }
}

__device__ inline void gl2lds16(const void* g, void* l) {
    __builtin_amdgcn_global_load_lds(
        (const __attribute__((address_space(1))) unsigned int*)g,
        (__attribute__((address_space(3))) unsigned int*)l, 16, 0, 0);
}

// ---------------- common epilogue: f32 out, mimic ref fp16 double-rounding ----------------
__device__ inline void epilogue(f32x4 acc[4][4], const float* bias, float* C,
                                float rs, int row0, int col0, int wr, int wc,
                                int lane, int N) {
    int crow0 = row0 + wr * 64;
    int ccol0 = col0 + wc * 64 + (lane & 15);
    int rsub = (lane >> 4) * 4;
#pragma unroll
    for (int n = 0; n < 4; ++n) {
        int col = ccol0 + n * 16;
        float bv = bias[col];   // fp16-exact value, upcast
#pragma unroll
        for (int m = 0; m < 4; ++m) {
#pragma unroll
            for (int j = 0; j < 4; ++j) {
                int row = crow0 + m * 16 + rsub + j;
                // ref: fp16(acc*rs) then fp16(+bias), compared in f32
                float t = __half2float(__float2half_rn(acc[m][n][j] * rs));
                C[(size_t)row * N + col] = __half2float(__float2half_rn(t + bv));
            }
        }
    }
}

// ---------------- Path A GEMM: pre-quantized bf16 tiles via global_load_lds ----------------
__global__ __launch_bounds__(256)
void gemm_kernel(const unsigned short* __restrict__ A,   // xq bf16 [M][K]
                 const unsigned short* __restrict__ B,   // wq bf16 [N][K]
                 const float* __restrict__ bias,
                 float* __restrict__ C,
                 const float* __restrict__ amax2,
                 int M, int N, int K) {
    __shared__ uint4 As4[TM * TK * 2 / 16];   // 16 KiB
    __shared__ uint4 Bs4[TN * TK * 2 / 16];   // 16 KiB
    char* As = (char*)As4;
    char* Bs = (char*)Bs4;

    int tid = threadIdx.x;
    int lane = tid & 63;
    int wave = tid >> 6;
    int row0 = blockIdx.y * TM;
    int col0 = blockIdx.x * TN;
    int wr = wave >> 1, wc = wave & 1;

    f32x4 acc[4][4];
#pragma unroll
    for (int m = 0; m < 4; ++m)
#pragma unroll
        for (int n = 0; n < 4; ++n)
            acc[m][n] = (f32x4){0.f, 0.f, 0.f, 0.f};

    int frow = lane & 15;
    int fksub = (lane >> 4) * 16;

    for (int kt = 0; kt < K; kt += TK) {
#pragma unroll
        for (int i = 0; i < 4; ++i) {
            int s = i * 256 + tid;
            int r = s >> 3, c = s & 7;
            gl2lds16(A + (size_t)(row0 + r) * K + kt + c * 8,
                     As + (i * 256 + wave * 64) * 16);
            gl2lds16(B + (size_t)(col0 + r) * K + kt + c * 8,
                     Bs + (i * 256 + wave * 64) * 16);
        }
        __syncthreads();

#pragma unroll
        for (int kk = 0; kk < 2; ++kk) {
            bf16x8 af[4], bfr[4];
#pragma unroll
            for (int m = 0; m < 4; ++m)
                af[m] = *(const bf16x8*)(As + (wr * 64 + m * 16 + frow) * (TK * 2) + kk * 64 + fksub);
#pragma unroll
            for (int n = 0; n < 4; ++n)
                bfr[n] = *(const bf16x8*)(Bs + (wc * 64 + n * 16 + frow) * (TK * 2) + kk * 64 + fksub);
#pragma unroll
            for (int m = 0; m < 4; ++m)
#pragma unroll
                for (int n = 0; n < 4; ++n)
                    acc[m][n] = __builtin_amdgcn_mfma_f32_16x16x32_bf16(af[m], bfr[n], acc[m][n], 0, 0, 0);
        }
        __syncthreads();
    }

    float ax = fmaxf(amax2[0], 1e-12f);
    float aw = fmaxf(amax2[1], 1e-12f);
    float rs = (ax / FP8MAX) * (aw / FP8MAX);
    epilogue(acc, bias, C, rs, row0, col0, wr, wc, lane, N);
}

// ---------------- Path B GEMM: fused reg-staged quant from f32 inputs ----------------
__global__ __launch_bounds__(256)
void gemm_fused(const float* __restrict__ X,   // [M][K] f32
                const float* __restrict__ W,   // [N][K] f32
                const float* __restrict__ bias,
                float* __restrict__ C,
                const float* __restrict__ amax2,
                int M, int N, int K) {
    __shared__ ushort8 As8[TM * TK / 8];   // 16 KiB bf16
    __shared__ ushort8 Bs8[TN * TK / 8];
    char* As = (char*)As8;
    char* Bs = (char*)Bs8;

    float ax = fmaxf(amax2[0], 1e-12f);
    float aw = fmaxf(amax2[1], 1e-12f);
    float sx = FP8MAX / ax, sw = FP8MAX / aw;

    int tid = threadIdx.x;
    int lane = tid & 63;
    int wave = tid >> 6;
    int row0 = blockIdx.y * TM;
    int col0 = blockIdx.x * TN;
    int wr = wave >> 1, wc = wave & 1;

    f32x4 acc[4][4];
#pragma unroll
    for (int m = 0; m < 4; ++m)
#pragma unroll
        for (int n = 0; n < 4; ++n)
            acc[m][n] = (f32x4){0.f, 0.f, 0.f, 0.f};

    int frow = lane & 15;
    int fksub = (lane >> 4) * 16;

    for (int kt = 0; kt < K; kt += TK) {
#pragma unroll
        for (int i = 0; i < 4; ++i) {
            int s = i * 256 + tid;
            int r = s >> 3, c = s & 7;
            const float* pa = X + (size_t)(row0 + r) * K + kt + c * 8;
            const float* pb = W + (size_t)(col0 + r) * K + kt + c * 8;
            float4 a0 = *(const float4*)pa, a1 = *(const float4*)(pa + 4);
            float4 b0 = *(const float4*)pb, b1 = *(const float4*)(pb + 4);
            *(ushort8*)(As + s * 16) = quant8f(a0, a1, sx);
            *(ushort8*)(Bs + s * 16) = quant8f(b0, b1, sw);
        }
        __syncthreads();

#pragma unroll
        for (int kk = 0; kk < 2; ++kk) {
            bf16x8 af[4], bfr[4];
#pragma unroll
            for (int m = 0; m < 4; ++m)
                af[m] = *(const bf16x8*)(As + (wr * 64 + m * 16 + frow) * (TK * 2) + kk * 64 + fksub);
#pragma unroll
            for (int n = 0; n < 4; ++n)
                bfr[n] = *(const bf16x8*)(Bs + (wc * 64 + n * 16 + frow) * (TK * 2) + kk * 64 + fksub);
#pragma unroll
            for (int m = 0; m < 4; ++m)
#pragma unroll
                for (int n = 0; n < 4; ++n)
                    acc[m][n] = __builtin_amdgcn_mfma_f32_16x16x32_bf16(af[m], bfr[n], acc[m][n], 0, 0, 0);
        }
        __syncthreads();
    }

    float rs = (ax / FP8MAX) * (aw / FP8MAX);
    epilogue(acc, bias, C, rs, row0, col0, wr, wc, lane, N);
}

extern "C" void kernel_launch(void* const* d_in, const int* in_sizes, int n_in,
                              void* d_out, int out_size, void* d_ws, size_t ws_size,
                              hipStream_t stream) {
    const float* x = (const float*)d_in[0];      // fp16 inputs arrive upcast to f32
    const float* w = (const float*)d_in[1];
    const float* bias = (const float*)d_in[2];
    float* out = (float*)d_out;                  // fp16 output compared as f32

    int N = in_sizes[2];
    int K = in_sizes[1] / N;
    int M = in_sizes[0] / K;

    // ws layout: bmx[1024] | bmw[1024] | amax2[2] | pad to 16 KiB | xq | wq
    float* bmx = (float*)d_ws;
    float* bmw = bmx + 1024;
    float* amax2 = bmx + 2048;
    unsigned short* xq = (unsigned short*)((char*)d_ws + 16384);
    unsigned short* wq = xq + (size_t)M * K;

    unsigned n4x = (unsigned)((size_t)M * K / 4);
    unsigned n4w = (unsigned)((size_t)N * K / 4);

    amax_stage1<<<1024, 256, 0, stream>>>(x, n4x, bmx);
    amax_stage1<<<1024, 256, 0, stream>>>(w, n4w, bmw);
    amax_stage2<<<2, 256, 0, stream>>>(bmx, 1024, amax2);  // [0]=ax, [1]=aw

    dim3 grid(N / TN, M / TM);
    size_t needA = ((size_t)M * K + (size_t)N * K) * 2 + 16384;

    if (ws_size >= needA) {
        // Path A: pre-quantize, then clean gl2lds GEMM
        quant_kernel<<<2048, 256, 0, stream>>>(x, (ushort8*)xq, amax2 + 0,
                                               (unsigned)((size_t)M * K / 8));
        quant_kernel<<<2048, 256, 0, stream>>>(w, (ushort8*)wq, amax2 + 1,
                                               (unsigned)((size_t)N * K / 8));
        gemm_kernel<<<grid, 256, 0, stream>>>(xq, wq, bias, out, amax2, M, N, K);
    } else {
        // Path B: fused reg-staged quantization (needs only ~8.2 KiB ws)
        gemm_fused<<<grid, 256, 0, stream>>>(x, w, bias, out, amax2, M, N, K);
    }
}

// Round 6
// 149.254 us; speedup vs baseline: 1.6823x; 1.6823x over previous
//
#include <hip/hip_runtime.h>
#include <hip/hip_fp16.h>

typedef __bf16 bf16x8 __attribute__((ext_vector_type(8)));
typedef float f32x4 __attribute__((ext_vector_type(4)));
typedef int i32x8 __attribute__((ext_vector_type(8)));
typedef unsigned short ushort8 __attribute__((ext_vector_type(8)));

#define TM 128
#define TN 128
#define TK 128          // fp8 bytes per K-step (K elements)
#define FP8MAX 448.0f
#define SCALE_ONE 0x7F7F7F7FU   // E8M0 127 = 2^0 per byte

// ---------------- amax stage 1: per-block max |x| over f32 input ----------------
__global__ __launch_bounds__(256)
void amax_stage1(const float* __restrict__ in, unsigned n4,
                 float* __restrict__ blockmax) {
    __shared__ float wmax[4];
    unsigned tid = blockIdx.x * 256 + threadIdx.x;
    unsigned stride = gridDim.x * 256;
    float m = 0.f;
    for (unsigned i = tid; i < n4; i += stride) {
        float4 v = *(const float4*)(in + (size_t)i * 4);
        m = fmaxf(m, fmaxf(fmaxf(fabsf(v.x), fabsf(v.y)), fmaxf(fabsf(v.z), fabsf(v.w))));
    }
#pragma unroll
    for (int off = 32; off > 0; off >>= 1)
        m = fmaxf(m, __shfl_down(m, off));
    if ((threadIdx.x & 63) == 0) wmax[threadIdx.x >> 6] = m;
    __syncthreads();
    if (threadIdx.x == 0)
        blockmax[blockIdx.x] = fmaxf(fmaxf(wmax[0], wmax[1]), fmaxf(wmax[2], wmax[3]));
}

// ---------------- amax stage 2: block b reduces bm[b*n .. b*n+n) -> outv[b] ----------------
__global__ __launch_bounds__(256)
void amax_stage2(const float* __restrict__ bm, int n, float* __restrict__ outv) {
    __shared__ float wmax[4];
    const float* p = bm + (size_t)blockIdx.x * n;
    float m = 0.f;
    for (int i = threadIdx.x; i < n; i += 256) m = fmaxf(m, p[i]);
#pragma unroll
    for (int off = 32; off > 0; off >>= 1)
        m = fmaxf(m, __shfl_down(m, off));
    if ((threadIdx.x & 63) == 0) wmax[threadIdx.x >> 6] = m;
    __syncthreads();
    if (threadIdx.x == 0)
        outv[blockIdx.x] = fmaxf(fmaxf(wmax[0], wmax[1]), fmaxf(wmax[2], wmax[3]));
}

// ---------------- quantize kernel: f32 -> e4m3 bytes (HW RNE, OCP) ----------------
__global__ __launch_bounds__(256)
void quant_kernel(const float* __restrict__ in, uint2* __restrict__ out,
                  const float* __restrict__ amax_p, unsigned n8) {
    float amax = fmaxf(*amax_p, 1e-12f);
    float scale = FP8MAX / amax;
    unsigned tid = blockIdx.x * 256 + threadIdx.x;
    unsigned stride = gridDim.x * 256;
    for (unsigned i = tid; i < n8; i += stride) {
        float4 lo = *(const float4*)(in + (size_t)i * 8);
        float4 hi = *(const float4*)(in + (size_t)i * 8 + 4);
        float f[8] = {lo.x, lo.y, lo.z, lo.w, hi.x, hi.y, hi.z, hi.w};
#pragma unroll
        for (int j = 0; j < 8; ++j)
            f[j] = fminf(fmaxf(f[j] * scale, -FP8MAX), FP8MAX);
        unsigned w0 = __builtin_amdgcn_cvt_pk_fp8_f32(f[0], f[1], 0u, false);
        w0 = __builtin_amdgcn_cvt_pk_fp8_f32(f[2], f[3], w0, true);
        unsigned w1 = __builtin_amdgcn_cvt_pk_fp8_f32(f[4], f[5], 0u, false);
        w1 = __builtin_amdgcn_cvt_pk_fp8_f32(f[6], f[7], w1, true);
        out[i] = make_uint2(w0, w1);
    }
}

__device__ inline void gl2lds16(const void* g, void* l) {
    __builtin_amdgcn_global_load_lds(
        (const __attribute__((address_space(1))) unsigned int*)g,
        (__attribute__((address_space(3))) unsigned int*)l, 16, 0, 0);
}

// ---------------- common epilogue: f32 out, mimic ref fp16 double-rounding ----------------
__device__ inline void epilogue(f32x4 acc[4][4], const float* bias, float* C,
                                float rs, int row0, int col0, int wr, int wc,
                                int lane, int N) {
    int crow0 = row0 + wr * 64;
    int ccol0 = col0 + wc * 64 + (lane & 15);
    int rsub = (lane >> 4) * 4;
#pragma unroll
    for (int n = 0; n < 4; ++n) {
        int col = ccol0 + n * 16;
        float bv = bias[col];
#pragma unroll
        for (int m = 0; m < 4; ++m) {
#pragma unroll
            for (int j = 0; j < 4; ++j) {
                int row = crow0 + m * 16 + rsub + j;
                float t = __half2float(__float2half_rn(acc[m][n][j] * rs));
                C[(size_t)row * N + col] = __half2float(__float2half_rn(t + bv));
            }
        }
    }
}

// ---------------- Path A GEMM: fp8 tiles, MX-scaled MFMA K=128 (unit scales) ----------------
__global__ __launch_bounds__(256)
void gemm_kernel(const unsigned char* __restrict__ A,   // xq e4m3 [M][K]
                 const unsigned char* __restrict__ B,   // wq e4m3 [N][K]
                 const float* __restrict__ bias,
                 float* __restrict__ C,
                 const float* __restrict__ amax2,
                 int M, int N, int K) {
    __shared__ uint4 As4[TM * TK / 16];   // 16 KiB fp8
    __shared__ uint4 Bs4[TN * TK / 16];   // 16 KiB
    char* As = (char*)As4;
    char* Bs = (char*)Bs4;

    int tid = threadIdx.x;
    int lane = tid & 63;
    int wave = tid >> 6;
    int row0 = blockIdx.y * TM;
    int col0 = blockIdx.x * TN;
    int wr = wave >> 1, wc = wave & 1;   // 2x2 waves, 64x64 each

    f32x4 acc[4][4];
#pragma unroll
    for (int m = 0; m < 4; ++m)
#pragma unroll
        for (int n = 0; n < 4; ++n)
            acc[m][n] = (f32x4){0.f, 0.f, 0.f, 0.f};

    int frow = lane & 15;
    int fk = (lane >> 4) * 32;   // this lane's 32-byte k-slice within 128

    for (int kt = 0; kt < K; kt += TK) {
        // stage A,B fp8 tiles: 1024 slots each; slot s = row (s>>3), 16B chunk (s&7)
#pragma unroll
        for (int i = 0; i < 4; ++i) {
            int s = i * 256 + tid;
            int r = s >> 3, c = s & 7;
            gl2lds16(A + (size_t)(row0 + r) * K + kt + c * 16,
                     As + (i * 256 + wave * 64) * 16);
            gl2lds16(B + (size_t)(col0 + r) * K + kt + c * 16,
                     Bs + (i * 256 + wave * 64) * 16);
        }
        __syncthreads();

        union { i32x8 v; uint4 q[2]; } af[4], bf[4];
#pragma unroll
        for (int m = 0; m < 4; ++m) {
            const char* p = As + (wr * 64 + m * 16 + frow) * TK + fk;
            af[m].q[0] = *(const uint4*)p;
            af[m].q[1] = *(const uint4*)(p + 16);
        }
#pragma unroll
        for (int n = 0; n < 4; ++n) {
            const char* p = Bs + (wc * 64 + n * 16 + frow) * TK + fk;
            bf[n].q[0] = *(const uint4*)p;
            bf[n].q[1] = *(const uint4*)(p + 16);
        }
#pragma unroll
        for (int m = 0; m < 4; ++m)
#pragma unroll
            for (int n = 0; n < 4; ++n)
                acc[m][n] = __builtin_amdgcn_mfma_scale_f32_16x16x128_f8f6f4(
                    af[m].v, bf[n].v, acc[m][n],
                    0, 0,                 // cbsz=fp8(e4m3), blgp=fp8(e4m3)
                    0, SCALE_ONE,         // opsel_a, scale_a = 1.0
                    0, SCALE_ONE);        // opsel_b, scale_b = 1.0
        __syncthreads();
    }

    float ax = fmaxf(amax2[0], 1e-12f);
    float aw = fmaxf(amax2[1], 1e-12f);
    float rs = (ax / FP8MAX) * (aw / FP8MAX);
    epilogue(acc, bias, C, rs, row0, col0, wr, wc, lane, N);
}

// ---------------- Path B GEMM (fallback, small ws): fused reg-staged quant, bf16 MFMA ----------------
__device__ inline ushort8 quant8f_bf16(float4 lo, float4 hi, float scale) {
    float f[8] = {lo.x, lo.y, lo.z, lo.w, hi.x, hi.y, hi.z, hi.w};
    ushort8 r;
#pragma unroll
    for (int j = 0; j < 4; ++j) {
        float f0 = fminf(fmaxf(f[2 * j] * scale, -FP8MAX), FP8MAX);
        float f1 = fminf(fmaxf(f[2 * j + 1] * scale, -FP8MAX), FP8MAX);
        unsigned pk = __builtin_amdgcn_cvt_pk_fp8_f32(f0, f1, 0u, false);
        float d0 = __builtin_amdgcn_cvt_f32_fp8(pk, 0);
        float d1 = __builtin_amdgcn_cvt_f32_fp8(pk, 1);
        r[2 * j]     = (unsigned short)(__float_as_uint(d0) >> 16);
        r[2 * j + 1] = (unsigned short)(__float_as_uint(d1) >> 16);
    }
    return r;
}

__global__ __launch_bounds__(256)
void gemm_fused(const float* __restrict__ X, const float* __restrict__ W,
                const float* __restrict__ bias, float* __restrict__ C,
                const float* __restrict__ amax2, int M, int N, int K) {
    __shared__ ushort8 As8[TM * 64 / 8];
    __shared__ ushort8 Bs8[TN * 64 / 8];
    char* As = (char*)As8;
    char* Bs = (char*)Bs8;

    float ax = fmaxf(amax2[0], 1e-12f);
    float aw = fmaxf(amax2[1], 1e-12f);
    float sx = FP8MAX / ax, sw = FP8MAX / aw;

    int tid = threadIdx.x;
    int lane = tid & 63;
    int wave = tid >> 6;
    int row0 = blockIdx.y * TM;
    int col0 = blockIdx.x * TN;
    int wr = wave >> 1, wc = wave & 1;

    f32x4 acc[4][4];
#pragma unroll
    for (int m = 0; m < 4; ++m)
#pragma unroll
        for (int n = 0; n < 4; ++n)
            acc[m][n] = (f32x4){0.f, 0.f, 0.f, 0.f};

    int frow = lane & 15;
    int fksub = (lane >> 4) * 16;

    for (int kt = 0; kt < K; kt += 64) {
#pragma unroll
        for (int i = 0; i < 4; ++i) {
            int s = i * 256 + tid;
            int r = s >> 3, c = s & 7;
            const float* pa = X + (size_t)(row0 + r) * K + kt + c * 8;
            const float* pb = W + (size_t)(col0 + r) * K + kt + c * 8;
            float4 a0 = *(const float4*)pa, a1 = *(const float4*)(pa + 4);
            float4 b0 = *(const float4*)pb, b1 = *(const float4*)(pb + 4);
            *(ushort8*)(As + s * 16) = quant8f_bf16(a0, a1, sx);
            *(ushort8*)(Bs + s * 16) = quant8f_bf16(b0, b1, sw);
        }
        __syncthreads();

#pragma unroll
        for (int kk = 0; kk < 2; ++kk) {
            bf16x8 af[4], bfr[4];
#pragma unroll
            for (int m = 0; m < 4; ++m)
                af[m] = *(const bf16x8*)(As + (wr * 64 + m * 16 + frow) * 128 + kk * 64 + fksub);
#pragma unroll
            for (int n = 0; n < 4; ++n)
                bfr[n] = *(const bf16x8*)(Bs + (wc * 64 + n * 16 + frow) * 128 + kk * 64 + fksub);
#pragma unroll
            for (int m = 0; m < 4; ++m)
#pragma unroll
                for (int n = 0; n < 4; ++n)
                    acc[m][n] = __builtin_amdgcn_mfma_f32_16x16x32_bf16(af[m], bfr[n], acc[m][n], 0, 0, 0);
        }
        __syncthreads();
    }

    float rs = (ax / FP8MAX) * (aw / FP8MAX);
    epilogue(acc, bias, C, rs, row0, col0, wr, wc, lane, N);
}

extern "C" void kernel_launch(void* const* d_in, const int* in_sizes, int n_in,
                              void* d_out, int out_size, void* d_ws, size_t ws_size,
                              hipStream_t stream) {
    const float* x = (const float*)d_in[0];      // fp16 inputs arrive upcast to f32
    const float* w = (const float*)d_in[1];
    const float* bias = (const float*)d_in[2];
    float* out = (float*)d_out;                  // fp16 output compared as f32

    int N = in_sizes[2];
    int K = in_sizes[1] / N;
    int M = in_sizes[0] / K;

    // ws layout: bmx[1024] | bmw[1024] | amax2[2] | pad to 16 KiB | xq(fp8) | wq(fp8)
    float* bmx = (float*)d_ws;
    float* bmw = bmx + 1024;
    float* amax2 = bmx + 2048;
    unsigned char* xq = (unsigned char*)d_ws + 16384;
    unsigned char* wq = xq + (size_t)M * K;

    unsigned n4x = (unsigned)((size_t)M * K / 4);
    unsigned n4w = (unsigned)((size_t)N * K / 4);

    amax_stage1<<<1024, 256, 0, stream>>>(x, n4x, bmx);
    amax_stage1<<<1024, 256, 0, stream>>>(w, n4w, bmw);
    amax_stage2<<<2, 256, 0, stream>>>(bmx, 1024, amax2);  // [0]=ax, [1]=aw

    dim3 grid(N / TN, M / TM);
    size_t needA = (size_t)M * K + (size_t)N * K + 16384;

    if (ws_size >= needA) {
        quant_kernel<<<2048, 256, 0, stream>>>(x, (uint2*)xq, amax2 + 0,
                                               (unsigned)((size_t)M * K / 8));
        quant_kernel<<<2048, 256, 0, stream>>>(w, (uint2*)wq, amax2 + 1,
                                               (unsigned)((size_t)N * K / 8));
        gemm_kernel<<<grid, 256, 0, stream>>>(xq, wq, bias, out, amax2, M, N, K);
    } else {
        gemm_fused<<<grid, 256, 0, stream>>>(x, w, bias, out, amax2, M, N, K);
    }
}

// Round 8
// 145.377 us; speedup vs baseline: 1.7271x; 1.0267x over previous
//
#include <hip/hip_runtime.h>
#include <hip/hip_fp16.h>

typedef __bf16 bf16x8 __attribute__((ext_vector_type(8)));
typedef float f32x4 __attribute__((ext_vector_type(4)));
typedef int i32x8 __attribute__((ext_vector_type(8)));
typedef unsigned short ushort8 __attribute__((ext_vector_type(8)));

#define BM 256
#define BN 128
#define BK 128                    // fp8 bytes = elements per K-tile
#define FP8MAX 448.0f
#define SCALE_ONE 0x7F7F7F7FU     // E8M0 127 = 2^0 per byte
#define A_BYTES (BM * BK)         // 32768
#define B_BYTES (BN * BK)         // 16384
#define SLOT_BYTES (A_BYTES + B_BYTES)   // 49152; 3 slots = 144 KiB

// ---------------- amax stage 1 (fused x+w): blocks [0,1024)->x, [1024,2048)->w ----------------
__global__ __launch_bounds__(256)
void amax_stage1(const float* __restrict__ x, unsigned n4x,
                 const float* __restrict__ w, unsigned n4w,
                 float* __restrict__ bm) {
    __shared__ float wmax[4];
    bool isw = blockIdx.x >= 1024;
    const float* in = isw ? w : x;
    unsigned n4 = isw ? n4w : n4x;
    unsigned tid = (blockIdx.x & 1023) * 256 + threadIdx.x;
    float m = 0.f;
    for (unsigned i = tid; i < n4; i += 1024 * 256) {
        float4 v = *(const float4*)(in + (size_t)i * 4);
        m = fmaxf(m, fmaxf(fmaxf(fabsf(v.x), fabsf(v.y)), fmaxf(fabsf(v.z), fabsf(v.w))));
    }
#pragma unroll
    for (int off = 32; off > 0; off >>= 1)
        m = fmaxf(m, __shfl_down(m, off));
    if ((threadIdx.x & 63) == 0) wmax[threadIdx.x >> 6] = m;
    __syncthreads();
    if (threadIdx.x == 0)
        bm[blockIdx.x] = fmaxf(fmaxf(wmax[0], wmax[1]), fmaxf(wmax[2], wmax[3]));
}

// ---------------- amax stage 2: block b reduces bm[b*1024 .. +1024) -> amax2[b] ----------------
__global__ __launch_bounds__(256)
void amax_stage2(const float* __restrict__ bm, float* __restrict__ outv) {
    __shared__ float wmax[4];
    const float* p = bm + (size_t)blockIdx.x * 1024;
    float m = 0.f;
    for (int i = threadIdx.x; i < 1024; i += 256) m = fmaxf(m, p[i]);
#pragma unroll
    for (int off = 32; off > 0; off >>= 1)
        m = fmaxf(m, __shfl_down(m, off));
    if ((threadIdx.x & 63) == 0) wmax[threadIdx.x >> 6] = m;
    __syncthreads();
    if (threadIdx.x == 0)
        outv[blockIdx.x] = fmaxf(fmaxf(wmax[0], wmax[1]), fmaxf(wmax[2], wmax[3]));
}

// ---------------- quantize (fused x+w): f32 -> e4m3 bytes (HW RNE, OCP) ----------------
__global__ __launch_bounds__(256)
void quant_kernel(const float* __restrict__ x, unsigned n8x,
                  const float* __restrict__ w, unsigned n8w,
                  unsigned char* __restrict__ xq, unsigned char* __restrict__ wq,
                  const float* __restrict__ amax2) {
    bool isw = blockIdx.x >= 2048;
    const float* in = isw ? w : x;
    uint2* out = (uint2*)(isw ? wq : xq);
    unsigned n8 = isw ? n8w : n8x;
    float amax = fmaxf(amax2[isw ? 1 : 0], 1e-12f);
    float scale = FP8MAX / amax;
    unsigned tid = (blockIdx.x & 2047) * 256 + threadIdx.x;
    for (unsigned i = tid; i < n8; i += 2048 * 256) {
        float4 lo = *(const float4*)(in + (size_t)i * 8);
        float4 hi = *(const float4*)(in + (size_t)i * 8 + 4);
        float f[8] = {lo.x, lo.y, lo.z, lo.w, hi.x, hi.y, hi.z, hi.w};
#pragma unroll
        for (int j = 0; j < 8; ++j)
            f[j] = fminf(fmaxf(f[j] * scale, -FP8MAX), FP8MAX);
        unsigned w0 = __builtin_amdgcn_cvt_pk_fp8_f32(f[0], f[1], 0u, false);
        w0 = __builtin_amdgcn_cvt_pk_fp8_f32(f[2], f[3], w0, true);
        unsigned w1 = __builtin_amdgcn_cvt_pk_fp8_f32(f[4], f[5], 0u, false);
        w1 = __builtin_amdgcn_cvt_pk_fp8_f32(f[6], f[7], w1, true);
        out[i] = make_uint2(w0, w1);
    }
}

__device__ inline void gl2lds16(const void* g, void* l) {
    __builtin_amdgcn_global_load_lds(
        (const __attribute__((address_space(1))) unsigned int*)g,
        (__attribute__((address_space(3))) unsigned int*)l, 16, 0, 0);
}

// ---------------- GEMM: 256x128 tile, 8 waves (64x64 each), 3-slot LDS pipeline ----------------
// LDS layout per slot: A [256 rows][128 B] then B [128 rows][128 B], both XOR-swizzled:
//   global chunk cc of row r lives at LDS chunk (cc ^ (r&7))  (16B chunks)
__global__ __launch_bounds__(512, 2)
void gemm_kernel(const unsigned char* __restrict__ A,   // xq e4m3 [M][K]
                 const unsigned char* __restrict__ B,   // wq e4m3 [N][K]
                 const float* __restrict__ bias,
                 float* __restrict__ C,
                 const float* __restrict__ amax2,
                 int M, int N, int K) {
    extern __shared__ char LDS[];

    int tid = threadIdx.x;
    int lane = tid & 63;
    int wave = tid >> 6;          // 0..7
    int wr = wave >> 1;           // 0..3: 64-row band
    int wc = wave & 1;            // 0..1: 64-col band
    int row0 = blockIdx.y * BM;
    int col0 = blockIdx.x * BN;

    f32x4 acc[4][4];
#pragma unroll
    for (int m = 0; m < 4; ++m)
#pragma unroll
        for (int n = 0; n < 4; ++n)
            acc[m][n] = (f32x4){0.f, 0.f, 0.f, 0.f};

    int frow = lane & 15;
    int g32 = (lane >> 4) * 32;   // lane's 32B k-slice base within the 128B row

    const int NT = K >> 7;        // K-tiles

    // stage K-tile t into slot si: linear LDS dest (gl2lds requirement), pre-swizzled global src
    auto STAGE = [&](int t, int si) {
        char* slot = LDS + si * SLOT_BYTES;
#pragma unroll
        for (int i = 0; i < 4; ++i) {           // A: 2048 chunks
            int s = i * 512 + tid;
            int r = s >> 3, c = s & 7;
            gl2lds16(A + (size_t)(row0 + r) * K + t * BK + ((c ^ (r & 7)) << 4),
                     slot + s * 16);
        }
#pragma unroll
        for (int i = 0; i < 2; ++i) {           // B: 1024 chunks
            int s = i * 512 + tid;
            int r = s >> 3, c = s & 7;
            gl2lds16(B + (size_t)(col0 + r) * K + t * BK + ((c ^ (r & 7)) << 4),
                     slot + A_BYTES + s * 16);
        }
    };

    // prologue: stage kt=0,1; wait for kt0 (kt1's 6 loads stay in flight)
    STAGE(0, 0);
    if (NT > 1) {
        STAGE(1, 1);
        __builtin_amdgcn_sched_barrier(0);
        asm volatile("s_waitcnt vmcnt(6)" ::: "memory");
    } else {
        __builtin_amdgcn_sched_barrier(0);
        asm volatile("s_waitcnt vmcnt(0)" ::: "memory");
    }
    __builtin_amdgcn_s_barrier();
    __builtin_amdgcn_sched_barrier(0);

    int cur = 0;
    for (int t = 0; t < NT; ++t) {
        // prefetch kt+2 into the slot consumed at iter t-1 (safe past last barrier)
        if (t + 2 < NT) {
            int stg = (cur == 0) ? 2 : cur - 1;
            STAGE(t + 2, stg);
        }

        char* As = LDS + cur * SLOT_BYTES;
        char* Bs = As + A_BYTES;
        union U { i32x8 v; uint4 q[2]; };
        U af[4], bf[4];
#pragma unroll
        for (int m = 0; m < 4; ++m) {
            int row = wr * 64 + m * 16 + frow;
            int c0 = g32 ^ ((row & 7) << 4);
            const char* p = As + row * 128;
            af[m].q[0] = *(const uint4*)(p + c0);
            af[m].q[1] = *(const uint4*)(p + (c0 ^ 16));
        }
#pragma unroll
        for (int n = 0; n < 4; ++n) {
            int row = wc * 64 + n * 16 + frow;
            int c0 = g32 ^ ((row & 7) << 4);
            const char* p = Bs + row * 128;
            bf[n].q[0] = *(const uint4*)(p + c0);
            bf[n].q[1] = *(const uint4*)(p + (c0 ^ 16));
        }

        __builtin_amdgcn_s_setprio(1);
#pragma unroll
        for (int m = 0; m < 4; ++m)
#pragma unroll
            for (int n = 0; n < 4; ++n)
                acc[m][n] = __builtin_amdgcn_mfma_scale_f32_16x16x128_f8f6f4(
                    af[m].v, bf[n].v, acc[m][n],
                    0, 0, 0, SCALE_ONE, 0, SCALE_ONE);
        __builtin_amdgcn_s_setprio(0);

        if (t + 1 < NT) {
            __builtin_amdgcn_sched_barrier(0);
            if (t + 2 < NT)
                asm volatile("s_waitcnt vmcnt(6)" ::: "memory");  // kt+1 resident; kt+2 in flight
            else
                asm volatile("s_waitcnt vmcnt(0)" ::: "memory");  // tail drain
            __builtin_amdgcn_s_barrier();
            __builtin_amdgcn_sched_barrier(0);
        }
        cur = (cur == 2) ? 0 : cur + 1;
    }

    // epilogue: out = f32(fp16(fp16(acc*rs) + bias))
    float ax = fmaxf(amax2[0], 1e-12f);
    float aw = fmaxf(amax2[1], 1e-12f);
    float rs = (ax / FP8MAX) * (aw / FP8MAX);

    int crow0 = row0 + wr * 64;
    int ccol0 = col0 + wc * 64 + frow;
    int rsub = (lane >> 4) * 4;
#pragma unroll
    for (int n = 0; n < 4; ++n) {
        int col = ccol0 + n * 16;
        float bv = bias[col];
#pragma unroll
        for (int m = 0; m < 4; ++m) {
#pragma unroll
            for (int j = 0; j < 4; ++j) {
                int row = crow0 + m * 16 + rsub + j;
                float tcl = __half2float(__float2half_rn(acc[m][n][j] * rs));
                C[(size_t)row * N + col] = __half2float(__float2half_rn(tcl + bv));
            }
        }
    }
}

// ---------------- fallback (tiny ws): fused reg-staged quant, bf16 MFMA, 128^2 ----------------
__device__ inline ushort8 quant8f_bf16(float4 lo, float4 hi, float scale) {
    float f[8] = {lo.x, lo.y, lo.z, lo.w, hi.x, hi.y, hi.z, hi.w};
    ushort8 r;
#pragma unroll
    for (int j = 0; j < 4; ++j) {
        float f0 = fminf(fmaxf(f[2 * j] * scale, -FP8MAX), FP8MAX);
        float f1 = fminf(fmaxf(f[2 * j + 1] * scale, -FP8MAX), FP8MAX);
        unsigned pk = __builtin_amdgcn_cvt_pk_fp8_f32(f0, f1, 0u, false);
        float d0 = __builtin_amdgcn_cvt_f32_fp8(pk, 0);
        float d1 = __builtin_amdgcn_cvt_f32_fp8(pk, 1);
        r[2 * j]     = (unsigned short)(__float_as_uint(d0) >> 16);
        r[2 * j + 1] = (unsigned short)(__float_as_uint(d1) >> 16);
    }
    return r;
}

__global__ __launch_bounds__(256)
void gemm_fused(const float* __restrict__ X, const float* __restrict__ W,
                const float* __restrict__ bias, float* __restrict__ C,
                const float* __restrict__ amax2, int M, int N, int K) {
    __shared__ ushort8 As8[128 * 64 / 8];
    __shared__ ushort8 Bs8[128 * 64 / 8];
    char* As = (char*)As8;
    char* Bs = (char*)Bs8;

    float ax = fmaxf(amax2[0], 1e-12f);
    float aw = fmaxf(amax2[1], 1e-12f);
    float sx = FP8MAX / ax, sw = FP8MAX / aw;

    int tid = threadIdx.x;
    int lane = tid & 63;
    int wave = tid >> 6;
    int row0 = blockIdx.y * 128;
    int col0 = blockIdx.x * 128;
    int wr = wave >> 1, wc = wave & 1;

    f32x4 acc[4][4];
#pragma unroll
    for (int m = 0; m < 4; ++m)
#pragma unroll
        for (int n = 0; n < 4; ++n)
            acc[m][n] = (f32x4){0.f, 0.f, 0.f, 0.f};

    int frow = lane & 15;
    int fksub = (lane >> 4) * 16;

    for (int kt = 0; kt < K; kt += 64) {
#pragma unroll
        for (int i = 0; i < 4; ++i) {
            int s = i * 256 + tid;
            int r = s >> 3, c = s & 7;
            const float* pa = X + (size_t)(row0 + r) * K + kt + c * 8;
            const float* pb = W + (size_t)(col0 + r) * K + kt + c * 8;
            float4 a0 = *(const float4*)pa, a1 = *(const float4*)(pa + 4);
            float4 b0 = *(const float4*)pb, b1 = *(const float4*)(pb + 4);
            *(ushort8*)(As + s * 16) = quant8f_bf16(a0, a1, sx);
            *(ushort8*)(Bs + s * 16) = quant8f_bf16(b0, b1, sw);
        }
        __syncthreads();

#pragma unroll
        for (int kk = 0; kk < 2; ++kk) {
            bf16x8 af[4], bfr[4];
#pragma unroll
            for (int m = 0; m < 4; ++m)
                af[m] = *(const bf16x8*)(As + (wr * 64 + m * 16 + frow) * 128 + kk * 64 + fksub);
#pragma unroll
            for (int n = 0; n < 4; ++n)
                bfr[n] = *(const bf16x8*)(Bs + (wc * 64 + n * 16 + frow) * 128 + kk * 64 + fksub);
#pragma unroll
            for (int m = 0; m < 4; ++m)
#pragma unroll
                for (int n = 0; n < 4; ++n)
                    acc[m][n] = __builtin_amdgcn_mfma_f32_16x16x32_bf16(af[m], bfr[n], acc[m][n], 0, 0, 0);
        }
        __syncthreads();
    }

    float rs = (ax / FP8MAX) * (aw / FP8MAX);
    int crow0 = row0 + wr * 64;
    int ccol0 = col0 + wc * 64 + frow;
    int rsub = (lane >> 4) * 4;
#pragma unroll
    for (int n = 0; n < 4; ++n) {
        int col = ccol0 + n * 16;
        float bv = bias[col];
#pragma unroll
        for (int m = 0; m < 4; ++m) {
#pragma unroll
            for (int j = 0; j < 4; ++j) {
                int row = crow0 + m * 16 + rsub + j;
                float t = __half2float(__float2half_rn(acc[m][n][j] * rs));
                C[(size_t)row * N + col] = __half2float(__float2half_rn(t + bv));
            }
        }
    }
}

extern "C" void kernel_launch(void* const* d_in, const int* in_sizes, int n_in,
                              void* d_out, int out_size, void* d_ws, size_t ws_size,
                              hipStream_t stream) {
    const float* x = (const float*)d_in[0];      // fp16 inputs arrive upcast to f32
    const float* w = (const float*)d_in[1];
    const float* bias = (const float*)d_in[2];
    float* out = (float*)d_out;                  // fp16 output compared as f32

    int N = in_sizes[2];
    int K = in_sizes[1] / N;
    int M = in_sizes[0] / K;

    // ws layout: bm[2048] | amax2[2] | pad to 16 KiB | xq(fp8) | wq(fp8)
    float* bm = (float*)d_ws;
    float* amax2 = bm + 2048;
    unsigned char* xq = (unsigned char*)d_ws + 16384;
    unsigned char* wq = xq + (size_t)M * K;

    unsigned n4x = (unsigned)((size_t)M * K / 4);
    unsigned n4w = (unsigned)((size_t)N * K / 4);

    amax_stage1<<<2048, 256, 0, stream>>>(x, n4x, w, n4w, bm);
    amax_stage2<<<2, 256, 0, stream>>>(bm, amax2);   // [0]=ax, [1]=aw

    size_t needA = (size_t)M * K + (size_t)N * K + 16384;

    if (ws_size >= needA && (M % BM) == 0 && (N % BN) == 0 && (K % BK) == 0 && K / BK >= 2) {
        quant_kernel<<<4096, 256, 0, stream>>>(x, (unsigned)((size_t)M * K / 8),
                                               w, (unsigned)((size_t)N * K / 8),
                                               xq, wq, amax2);
        dim3 grid(N / BN, M / BM);
        gemm_kernel<<<grid, 512, 3 * SLOT_BYTES, stream>>>(xq, wq, bias, out, amax2, M, N, K);
    } else {
        dim3 grid(N / 128, M / 128);
        gemm_fused<<<grid, 256, 0, stream>>>(x, w, bias, out, amax2, M, N, K);
    }
}

// Round 9
// 130.350 us; speedup vs baseline: 1.9263x; 1.1153x over previous
//
#include <hip/hip_runtime.h>
#include <hip/hip_fp16.h>

typedef __bf16 bf16x8 __attribute__((ext_vector_type(8)));
typedef float f32x4 __attribute__((ext_vector_type(4)));
typedef int i32x8 __attribute__((ext_vector_type(8)));
typedef unsigned short ushort8 __attribute__((ext_vector_type(8)));

#define BM 256
#define BN 256
#define BK 128                    // fp8 bytes = elements per K-tile
#define FP8MAX 448.0f
#define SCALE_ONE 0x7F7F7F7FU     // E8M0 127 = 2^0 per byte
#define A_BYTES (BM * BK)         // 32768
#define B_BYTES (BN * BK)         // 32768
#define SLOT_BYTES (A_BYTES + B_BYTES)   // 65536; 2 slots = 128 KiB

// ---------------- amax stage 1 (fused x+w): blocks [0,1024)->x, [1024,2048)->w ----------------
__global__ __launch_bounds__(256)
void amax_stage1(const float* __restrict__ x, unsigned n4x,
                 const float* __restrict__ w, unsigned n4w,
                 float* __restrict__ bm) {
    __shared__ float wmax[4];
    bool isw = blockIdx.x >= 1024;
    const float* in = isw ? w : x;
    unsigned n4 = isw ? n4w : n4x;
    unsigned tid = (blockIdx.x & 1023) * 256 + threadIdx.x;
    float m = 0.f;
    for (unsigned i = tid; i < n4; i += 1024 * 256) {
        float4 v = *(const float4*)(in + (size_t)i * 4);
        m = fmaxf(m, fmaxf(fmaxf(fabsf(v.x), fabsf(v.y)), fmaxf(fabsf(v.z), fabsf(v.w))));
    }
#pragma unroll
    for (int off = 32; off > 0; off >>= 1)
        m = fmaxf(m, __shfl_down(m, off));
    if ((threadIdx.x & 63) == 0) wmax[threadIdx.x >> 6] = m;
    __syncthreads();
    if (threadIdx.x == 0)
        bm[blockIdx.x] = fmaxf(fmaxf(wmax[0], wmax[1]), fmaxf(wmax[2], wmax[3]));
}

// ---------------- amax stage 2: block b reduces bm[b*1024 .. +1024) -> amax2[b] ----------------
__global__ __launch_bounds__(256)
void amax_stage2(const float* __restrict__ bm, float* __restrict__ outv) {
    __shared__ float wmax[4];
    const float* p = bm + (size_t)blockIdx.x * 1024;
    float m = 0.f;
    for (int i = threadIdx.x; i < 1024; i += 256) m = fmaxf(m, p[i]);
#pragma unroll
    for (int off = 32; off > 0; off >>= 1)
        m = fmaxf(m, __shfl_down(m, off));
    if ((threadIdx.x & 63) == 0) wmax[threadIdx.x >> 6] = m;
    __syncthreads();
    if (threadIdx.x == 0)
        outv[blockIdx.x] = fmaxf(fmaxf(wmax[0], wmax[1]), fmaxf(wmax[2], wmax[3]));
}

// ---------------- quantize (fused x+w): f32 -> e4m3 bytes (HW RNE, OCP) ----------------
__global__ __launch_bounds__(256)
void quant_kernel(const float* __restrict__ x, unsigned n8x,
                  const float* __restrict__ w, unsigned n8w,
                  unsigned char* __restrict__ xq, unsigned char* __restrict__ wq,
                  const float* __restrict__ amax2) {
    bool isw = blockIdx.x >= 2048;
    const float* in = isw ? w : x;
    uint2* out = (uint2*)(isw ? wq : xq);
    unsigned n8 = isw ? n8w : n8x;
    float amax = fmaxf(amax2[isw ? 1 : 0], 1e-12f);
    float scale = FP8MAX / amax;
    unsigned tid = (blockIdx.x & 2047) * 256 + threadIdx.x;
    for (unsigned i = tid; i < n8; i += 2048 * 256) {
        float4 lo = *(const float4*)(in + (size_t)i * 8);
        float4 hi = *(const float4*)(in + (size_t)i * 8 + 4);
        float f[8] = {lo.x, lo.y, lo.z, lo.w, hi.x, hi.y, hi.z, hi.w};
#pragma unroll
        for (int j = 0; j < 8; ++j)
            f[j] = fminf(fmaxf(f[j] * scale, -FP8MAX), FP8MAX);
        unsigned w0 = __builtin_amdgcn_cvt_pk_fp8_f32(f[0], f[1], 0u, false);
        w0 = __builtin_amdgcn_cvt_pk_fp8_f32(f[2], f[3], w0, true);
        unsigned w1 = __builtin_amdgcn_cvt_pk_fp8_f32(f[4], f[5], 0u, false);
        w1 = __builtin_amdgcn_cvt_pk_fp8_f32(f[6], f[7], w1, true);
        out[i] = make_uint2(w0, w1);
    }
}

__device__ inline void gl2lds16(const void* g, void* l) {
    __builtin_amdgcn_global_load_lds(
        (const __attribute__((address_space(1))) unsigned int*)g,
        (__attribute__((address_space(3))) unsigned int*)l, 16, 0, 0);
}

// ---------------- GEMM: 256x256 tile, 8 waves (128x64 each), 2-slot double buffer ----------------
// Per slot: A [256 rows][128 B] then B [256 rows][128 B]; XOR-swizzled per 16B chunk:
//   LDS chunk c of row r holds global chunk (c ^ (r&7)).
__global__ __launch_bounds__(512, 2)
void gemm_kernel(const unsigned char* __restrict__ A,   // xq e4m3 [M][K]
                 const unsigned char* __restrict__ B,   // wq e4m3 [N][K]
                 const float* __restrict__ bias,
                 float* __restrict__ C,
                 const float* __restrict__ amax2,
                 int M, int N, int K) {
    extern __shared__ char LDS[];

    int tid = threadIdx.x;
    int lane = tid & 63;
    int wave = tid >> 6;          // 0..7
    int wr = wave >> 2;           // 0..1: 128-row band
    int wcl = wave & 3;           // 0..3: 64-col band

    // bijective XCD swizzle (m204): consecutive swz within an XCD share the A-panel
    int nwg = gridDim.x;
    int nbx = N / BN;
    int q = nwg >> 3, r = nwg & 7;
    int xcd = blockIdx.x & 7, pos = blockIdx.x >> 3;
    int swz = (xcd < r ? xcd * (q + 1) : r * (q + 1) + (xcd - r) * q) + pos;
    int row0 = (swz / nbx) * BM;
    int col0 = (swz % nbx) * BN;

    f32x4 acc[8][4];
#pragma unroll
    for (int m = 0; m < 8; ++m)
#pragma unroll
        for (int n = 0; n < 4; ++n)
            acc[m][n] = (f32x4){0.f, 0.f, 0.f, 0.f};

    int frow = lane & 15;
    int g32 = (lane >> 4) * 32;   // lane's 32B k-slice base within the 128B row

    const int NT = K >> 7;        // K-tiles

    // stage K-tile t into slot si: linear LDS dest, pre-swizzled global source
    auto STAGE = [&](int t, int si) {
        char* slot = LDS + si * SLOT_BYTES;
#pragma unroll
        for (int i = 0; i < 4; ++i) {           // A: 2048 chunks
            int s = i * 512 + tid;
            int rr = s >> 3, c = s & 7;
            gl2lds16(A + (size_t)(row0 + rr) * K + t * BK + ((c ^ (rr & 7)) << 4),
                     slot + s * 16);
        }
#pragma unroll
        for (int i = 0; i < 4; ++i) {           // B: 2048 chunks
            int s = i * 512 + tid;
            int rr = s >> 3, c = s & 7;
            gl2lds16(B + (size_t)(col0 + rr) * K + t * BK + ((c ^ (rr & 7)) << 4),
                     slot + A_BYTES + s * 16);
        }
    };

    union U { i32x8 v; uint4 q[2]; };
    auto LDF = [&](U& u, const char* base, int row) {
        int c0 = g32 ^ ((row & 7) << 4);
        const char* p = base + row * 128;
        u.q[0] = *(const uint4*)(p + c0);
        u.q[1] = *(const uint4*)(p + (c0 ^ 16));
    };

    STAGE(0, 0);
    __syncthreads();              // vmcnt(0)+barrier: tile 0 resident

    int cur = 0;
    for (int t = 0; t < NT; ++t) {
        if (t + 1 < NT) STAGE(t + 1, cur ^ 1);   // issue-early: hides under compute

        const char* As = LDS + cur * SLOT_BYTES;
        const char* Bs = As + A_BYTES;

        U bf[4];
#pragma unroll
        for (int n = 0; n < 4; ++n)
            LDF(bf[n], Bs, wcl * 64 + n * 16 + frow);

        U af[8];
        LDF(af[0], As, wr * 128 + frow);
        LDF(af[1], As, wr * 128 + 16 + frow);

        __builtin_amdgcn_s_setprio(1);
#pragma unroll
        for (int m = 0; m < 8; ++m) {
            if (m + 2 < 8)
                LDF(af[m + 2], As, wr * 128 + (m + 2) * 16 + frow);  // 2-deep reg prefetch
#pragma unroll
            for (int n = 0; n < 4; ++n)
                acc[m][n] = __builtin_amdgcn_mfma_scale_f32_16x16x128_f8f6f4(
                    af[m].v, bf[n].v, acc[m][n],
                    0, 0, 0, SCALE_ONE, 0, SCALE_ONE);
        }
        __builtin_amdgcn_s_setprio(0);

        __syncthreads();          // drains vmcnt(0) (t+1 loads issued ~2000 cyc ago) + flip
        cur ^= 1;
    }

    // epilogue: out = f32(fp16(fp16(acc*rs) + bias))
    float ax = fmaxf(amax2[0], 1e-12f);
    float aw = fmaxf(amax2[1], 1e-12f);
    float rs = (ax / FP8MAX) * (aw / FP8MAX);

    int crow0 = row0 + wr * 128;
    int ccol0 = col0 + wcl * 64 + frow;
    int rsub = (lane >> 4) * 4;
#pragma unroll
    for (int n = 0; n < 4; ++n) {
        int col = ccol0 + n * 16;
        float bv = bias[col];
#pragma unroll
        for (int m = 0; m < 8; ++m) {
#pragma unroll
            for (int j = 0; j < 4; ++j) {
                int row = crow0 + m * 16 + rsub + j;
                float tcl = __half2float(__float2half_rn(acc[m][n][j] * rs));
                C[(size_t)row * N + col] = __half2float(__float2half_rn(tcl + bv));
            }
        }
    }
}

// ---------------- fallback (tiny ws / odd shapes): fused reg-staged quant, bf16 MFMA ----------------
__device__ inline ushort8 quant8f_bf16(float4 lo, float4 hi, float scale) {
    float f[8] = {lo.x, lo.y, lo.z, lo.w, hi.x, hi.y, hi.z, hi.w};
    ushort8 r;
#pragma unroll
    for (int j = 0; j < 4; ++j) {
        float f0 = fminf(fmaxf(f[2 * j] * scale, -FP8MAX), FP8MAX);
        float f1 = fminf(fmaxf(f[2 * j + 1] * scale, -FP8MAX), FP8MAX);
        unsigned pk = __builtin_amdgcn_cvt_pk_fp8_f32(f0, f1, 0u, false);
        float d0 = __builtin_amdgcn_cvt_f32_fp8(pk, 0);
        float d1 = __builtin_amdgcn_cvt_f32_fp8(pk, 1);
        r[2 * j]     = (unsigned short)(__float_as_uint(d0) >> 16);
        r[2 * j + 1] = (unsigned short)(__float_as_uint(d1) >> 16);
    }
    return r;
}

__global__ __launch_bounds__(256)
void gemm_fused(const float* __restrict__ X, const float* __restrict__ W,
                const float* __restrict__ bias, float* __restrict__ C,
                const float* __restrict__ amax2, int M, int N, int K) {
    __shared__ ushort8 As8[128 * 64 / 8];
    __shared__ ushort8 Bs8[128 * 64 / 8];
    char* As = (char*)As8;
    char* Bs = (char*)Bs8;

    float ax = fmaxf(amax2[0], 1e-12f);
    float aw = fmaxf(amax2[1], 1e-12f);
    float sx = FP8MAX / ax, sw = FP8MAX / aw;

    int tid = threadIdx.x;
    int lane = tid & 63;
    int wave = tid >> 6;
    int row0 = blockIdx.y * 128;
    int col0 = blockIdx.x * 128;
    int wr = wave >> 1, wc = wave & 1;

    f32x4 acc[4][4];
#pragma unroll
    for (int m = 0; m < 4; ++m)
#pragma unroll
        for (int n = 0; n < 4; ++n)
            acc[m][n] = (f32x4){0.f, 0.f, 0.f, 0.f};

    int frow = lane & 15;
    int fksub = (lane >> 4) * 16;

    for (int kt = 0; kt < K; kt += 64) {
#pragma unroll
        for (int i = 0; i < 4; ++i) {
            int s = i * 256 + tid;
            int r = s >> 3, c = s & 7;
            const float* pa = X + (size_t)(row0 + r) * K + kt + c * 8;
            const float* pb = W + (size_t)(col0 + r) * K + kt + c * 8;
            float4 a0 = *(const float4*)pa, a1 = *(const float4*)(pa + 4);
            float4 b0 = *(const float4*)pb, b1 = *(const float4*)(pb + 4);
            *(ushort8*)(As + s * 16) = quant8f_bf16(a0, a1, sx);
            *(ushort8*)(Bs + s * 16) = quant8f_bf16(b0, b1, sw);
        }
        __syncthreads();

#pragma unroll
        for (int kk = 0; kk < 2; ++kk) {
            bf16x8 af[4], bfr[4];
#pragma unroll
            for (int m = 0; m < 4; ++m)
                af[m] = *(const bf16x8*)(As + (wr * 64 + m * 16 + frow) * 128 + kk * 64 + fksub);
#pragma unroll
            for (int n = 0; n < 4; ++n)
                bfr[n] = *(const bf16x8*)(Bs + (wc * 64 + n * 16 + frow) * 128 + kk * 64 + fksub);
#pragma unroll
            for (int m = 0; m < 4; ++m)
#pragma unroll
                for (int n = 0; n < 4; ++n)
                    acc[m][n] = __builtin_amdgcn_mfma_f32_16x16x32_bf16(af[m], bfr[n], acc[m][n], 0, 0, 0);
        }
        __syncthreads();
    }

    float rs = (ax / FP8MAX) * (aw / FP8MAX);
    int crow0 = row0 + wr * 64;
    int ccol0 = col0 + wc * 64 + frow;
    int rsub = (lane >> 4) * 4;
#pragma unroll
    for (int n = 0; n < 4; ++n) {
        int col = ccol0 + n * 16;
        float bv = bias[col];
#pragma unroll
        for (int m = 0; m < 4; ++m) {
#pragma unroll
            for (int j = 0; j < 4; ++j) {
                int row = crow0 + m * 16 + rsub + j;
                float t = __half2float(__float2half_rn(acc[m][n][j] * rs));
                C[(size_t)row * N + col] = __half2float(__float2half_rn(t + bv));
            }
        }
    }
}

extern "C" void kernel_launch(void* const* d_in, const int* in_sizes, int n_in,
                              void* d_out, int out_size, void* d_ws, size_t ws_size,
                              hipStream_t stream) {
    const float* x = (const float*)d_in[0];      // fp16 inputs arrive upcast to f32
    const float* w = (const float*)d_in[1];
    const float* bias = (const float*)d_in[2];
    float* out = (float*)d_out;                  // fp16 output compared as f32

    int N = in_sizes[2];
    int K = in_sizes[1] / N;
    int M = in_sizes[0] / K;

    // ws layout: bm[2048] | amax2[2] | pad to 16 KiB | xq(fp8) | wq(fp8)
    float* bm = (float*)d_ws;
    float* amax2 = bm + 2048;
    unsigned char* xq = (unsigned char*)d_ws + 16384;
    unsigned char* wq = xq + (size_t)M * K;

    unsigned n4x = (unsigned)((size_t)M * K / 4);
    unsigned n4w = (unsigned)((size_t)N * K / 4);

    amax_stage1<<<2048, 256, 0, stream>>>(x, n4x, w, n4w, bm);
    amax_stage2<<<2, 256, 0, stream>>>(bm, amax2);   // [0]=ax, [1]=aw

    size_t needA = (size_t)M * K + (size_t)N * K + 16384;

    if (ws_size >= needA && (M % BM) == 0 && (N % BN) == 0 && (K % BK) == 0 && K / BK >= 2) {
        quant_kernel<<<4096, 256, 0, stream>>>(x, (unsigned)((size_t)M * K / 8),
                                               w, (unsigned)((size_t)N * K / 8),
                                               xq, wq, amax2);
        int nwg = (M / BM) * (N / BN);
        gemm_kernel<<<nwg, 512, 2 * SLOT_BYTES, stream>>>(xq, wq, bias, out, amax2, M, N, K);
    } else {
        dim3 grid(N / 128, M / 128);
        gemm_fused<<<grid, 256, 0, stream>>>(x, w, bias, out, amax2, M, N, K);
    }
}